// Round 2
// baseline (1099.136 us; speedup 1.0000x reference)
//
#include <hip/hip_runtime.h>

// QJLSketch: H=32, G=128, N=64, D=128, S=256, K=8
// d_out (float32, concatenated):
//   [0,        8388608): hash_inlier  [32,128,64,32] byte values as floats
//   [8388608, 12582912): hash_outlier [32,128,64,16] byte values as floats
//   [12582912,12845056): scores       [32, 128*64]
//
// Precision strategy (hypothesis B): reference signs come from an f32
// sequential ascending-d fused-FMA chain (BLAS-microkernel semantics).
// We replicate it bit-exactly: per (n,s), acc = fmaf(key[d], proj[s][d], acc)
// for d = 0..127 in order. Masked (zero) terms are bitwise no-ops, so:
//   - inlier chain  == full-d chain with proj registers zeroed at outlier dims
//   - outlier chain == chain over SORTED unique outlier dims only

constexpr int cH = 32, cG = 128, cN = 64, cD = 128, cS = 256, cK = 8;
constexpr int HASH_OUT_BASE = cH * cG * cN * (cS / 8);              // 8388608
constexpr int SCORE_BASE    = HASH_OUT_BASE + cH * cG * cN * (cS / 16); // 12582912

__global__ __launch_bounds__(256) void qjl_main(
    const float* __restrict__ data,      // [H*G, N, D]
    const float* __restrict__ query,     // [H, D]
    const int*   __restrict__ oidx,      // [H*G, K]
    const float* __restrict__ norm_data, // [H*G, N]
    const float* __restrict__ projq,     // [S, D]
    const float* __restrict__ projs,     // [D, S]
    float* __restrict__ out)
{
    const int b    = blockIdx.x;      // h*G + g
    const int t    = threadIdx.x;     // == s (projection index)
    const int lane = t & 63;
    const int w    = t >> 6;
    const int h    = b >> 7;          // G = 128

    __shared__ float ipPart[cN * 4];

    // --- unique outlier indices, SORTED ascending (redundant per thread) ---
    int u[cK];
    int U = 0;
    for (int k = 0; k < cK; ++k) {
        int v = oidx[b * cK + k];
        bool dup = false;
        for (int j = 0; j < U; ++j) dup = dup || (u[j] == v);
        if (!dup) u[U++] = v;
    }
    for (int i = 1; i < U; ++i) {          // insertion sort ascending
        int key = u[i], j = i - 1;
        while (j >= 0 && u[j] > key) { u[j + 1] = u[j]; --j; }
        u[j + 1] = key;
    }
    unsigned long long m0 = 0, m1 = 0;     // 128-bit outlier mask
    for (int k = 0; k < U; ++k) {
        int v = u[k];
        if (v < 64) m0 |= 1ull << v; else m1 |= 1ull << (v - 64);
    }
    int   ui[cK];
    float prO[cK];
    #pragma unroll
    for (int k = 0; k < cK; ++k) ui[k] = (k < cK) && (k < U) ? u[k] : 0;
    #pragma unroll
    for (int k = 0; k < cK; ++k) prO[k] = (k < U) ? projq[t * cD + ui[k]] : 0.0f;

    // --- masked proj row in VGPRs (zeroed at outlier dims) ---
    float prowM[cD];
    {
        const float4* p4 = reinterpret_cast<const float4*>(projq + t * cD);
        #pragma unroll
        for (int j = 0; j < cD / 4; ++j) {
            float4 v = p4[j];
            float tmp[4] = { v.x, v.y, v.z, v.w };
            #pragma unroll
            for (int e = 0; e < 4; ++e) {
                int d = j * 4 + e;
                bool msk = (((d < 64) ? (m0 >> d) : (m1 >> (d - 64))) & 1ull) != 0;
                prowM[d] = msk ? 0.0f : tmp[e];
            }
        }
    }

    // --- sketched_q[h][s]: f32 sequential chain (feeds scores, 2% tol) ---
    float qv = 0.0f;
    for (int d = 0; d < cD; ++d)
        qv = fmaf(query[h * cD + d], projs[d * cS + t], qv);

    const float* __restrict__ chunk = data + (size_t)b * (cN * cD);

    for (int n0 = 0; n0 < cN; n0 += 2) {
        const float* r0 = chunk + n0 * cD;   // wave-uniform → scalar loads
        const float* r1 = r0 + cD;
        float a0 = 0.0f, a1 = 0.0f;
        #pragma unroll
        for (int d = 0; d < cD; ++d) {       // sequential ascending-d chains
            a0 = fmaf(r0[d], prowM[d], a0);
            a1 = fmaf(r1[d], prowM[d], a1);
        }
        float o0 = 0.0f, o1 = 0.0f;
        #pragma unroll
        for (int k = 0; k < cK; ++k) {       // sorted outlier chain
            float d0 = (k < U) ? r0[ui[k]] : 0.0f;
            float d1 = (k < U) ? r1[ui[k]] : 0.0f;
            o0 = fmaf(d0, prO[k], o0);
            o1 = fmaf(d1, prO[k], o1);
        }
        #pragma unroll
        for (int q = 0; q < 2; ++q) {
            const int nn = n0 + q;
            const float skIn  = q ? a1 : a0;
            const float skOut = q ? o1 : o0;
            const bool bitIn = skIn > 0.0f;
            unsigned long long mIn  = __ballot(bitIn);
            unsigned long long mOut = __ballot(skOut > 0.0f);

            float v = bitIn ? qv : -qv;
            #pragma unroll
            for (int off = 32; off > 0; off >>= 1)
                v += __shfl_down(v, off);
            if (lane == 0) ipPart[nn * 4 + w] = v;

            if (lane < 8) {
                out[(size_t)b * (cN * 32) + nn * 32 + w * 8 + lane] =
                    (float)((mIn >> (8 * lane)) & 0xFFull);
                if (w < 2) {
                    out[HASH_OUT_BASE + (size_t)b * (cN * 16) + nn * 16 + w * 8 + lane] =
                        (float)((mOut >> (8 * lane)) & 0xFFull);
                }
            }
        }
    }

    __syncthreads();
    if (t < cN) {
        float ip = ipPart[t * 4 + 0] + ipPart[t * 4 + 1]
                 + ipPart[t * 4 + 2] + ipPart[t * 4 + 3];
        const float scl = 0.0048957583f;   // sqrt(pi/2)/256
        out[SCORE_BASE + b * cN + t] = scl * norm_data[b * cN + t] * ip;
    }
}

extern "C" void kernel_launch(void* const* d_in, const int* in_sizes, int n_in,
                              void* d_out, int out_size, void* d_ws, size_t ws_size,
                              hipStream_t stream) {
    const float* data      = (const float*)d_in[0];
    const float* query     = (const float*)d_in[1];
    const int*   oidx      = (const int*)d_in[2];
    const float* norm_data = (const float*)d_in[3];
    // d_in[4] = norm_outlier: unused by the reference
    const float* projq     = (const float*)d_in[5];  // proj_dir_quant [S,D]
    const float* projs     = (const float*)d_in[6];  // proj_dir_score [D,S]
    float* out = (float*)d_out;

    qjl_main<<<cH * cG, 256, 0, stream>>>(data, query, oidx, norm_data, projq, projs, out);
}

// Round 3
// 822.485 us; speedup vs baseline: 1.3364x; 1.3364x over previous
//
#include <hip/hip_runtime.h>

// QJLSketch: H=32, G=128, N=64, D=128, S=256, K=8
// d_out (float32, concatenated):
//   [0,        8388608): hash_inlier  [32,128,64,32] byte values as floats
//   [8388608, 12582912): hash_outlier [32,128,64,16] byte values as floats
//   [12582912,12845056): scores       [32, 128*64]
//
// Bit-exactness: reference signs come from an f32 sequential ascending-d fused-FMA
// chain. Masked (+0) proj terms are bitwise no-ops in the chain, so the inlier
// chain == full-d chain with proj zeroed at outlier dims; the outlier chain runs
// over SORTED unique outlier dims. d is chunked 8x16 purely for register
// residency; per-(n,s) chain order remains globally ascending in d.

constexpr int cH = 32, cG = 128, cN = 64, cD = 128, cS = 256, cK = 8;
constexpr int HASH_OUT_BASE = cH * cG * cN * (cS / 8);                  // 8388608
constexpr int SCORE_BASE    = HASH_OUT_BASE + cH * cG * cN * (cS / 16); // 12582912
constexpr int ROWS = 32;            // rows per block (N split in halves)

// --- tiny precompute: sketched_q[h][s] = sequential-chain dot(query[h], projs[:,s]) ---
__global__ __launch_bounds__(256) void qjl_qv(
    const float* __restrict__ query,   // [H, D]
    const float* __restrict__ projs,   // [D, S]
    float* __restrict__ qv_out)        // [H, S]
{
    const int h = blockIdx.x, s = threadIdx.x;
    float qa = 0.0f;
    for (int d = 0; d < cD; ++d)
        qa = fmaf(query[h * cD + d], projs[d * cS + s], qa);
    qv_out[h * cS + s] = qa;
}

__global__ __launch_bounds__(256) void qjl_main(
    const float* __restrict__ data,      // [H*G, N, D]
    const float* __restrict__ query,     // [H, D]
    const int*   __restrict__ oidx,      // [H*G, K]
    const float* __restrict__ norm_data, // [H*G, N]
    const float* __restrict__ projq,     // [S, D]
    const float* __restrict__ projs,     // [D, S]
    const float* __restrict__ qv_ws,     // [H, S] or nullptr
    float* __restrict__ out)
{
    const int b2   = blockIdx.x;      // 0..8191
    const int b    = b2 >> 1;         // h*G + g
    const int half = b2 & 1;
    const int t    = threadIdx.x;     // == s
    const int lane = t & 63;
    const int w    = t >> 6;
    const int h    = b >> 7;

    __shared__ float ipPart[ROWS * 4];

    // --- unique outlier indices, SORTED ascending (redundant per thread) ---
    int u[cK];
    int U = 0;
    for (int k = 0; k < cK; ++k) {
        int v = oidx[b * cK + k];
        bool dup = false;
        for (int j = 0; j < U; ++j) dup = dup || (u[j] == v);
        if (!dup) u[U++] = v;
    }
    for (int i = 1; i < U; ++i) {
        int key = u[i], j = i - 1;
        while (j >= 0 && u[j] > key) { u[j + 1] = u[j]; --j; }
        u[j + 1] = key;
    }
    unsigned long long m0 = 0, m1 = 0;     // 128-bit outlier-dim mask
    for (int k = 0; k < U; ++k) {
        int v = u[k];
        if (v < 64) m0 |= 1ull << v; else m1 |= 1ull << (v - 64);
    }
    int   ui[cK];
    float prO[cK];
    #pragma unroll
    for (int k = 0; k < cK; ++k) ui[k] = (k < U) ? u[k] : 0;
    #pragma unroll
    for (int k = 0; k < cK; ++k) prO[k] = (k < U) ? projq[t * cD + ui[k]] : 0.0f;

    // --- sketched_q value for this (h, s) ---
    float qv;
    if (qv_ws) {
        qv = qv_ws[h * cS + t];
    } else {
        float qa = 0.0f;
        for (int d = 0; d < cD; ++d)
            qa = fmaf(query[h * cD + d], projs[d * cS + t], qa);
        qv = qa;
    }

    const float* __restrict__ chunk = data + (size_t)b * (cN * cD) + half * (ROWS * cD);

    // --- main sketch: 32 persistent accumulators, d chunked 8x16 ---
    float acc[ROWS];
    #pragma unroll
    for (int n = 0; n < ROWS; ++n) acc[n] = 0.0f;

    for (int dc = 0; dc < cD / 16; ++dc) {
        // masked proj chunk in registers (zeroed at outlier dims)
        float pm[16];
        {
            const float4* p4 = reinterpret_cast<const float4*>(projq + t * cD + dc * 16);
            #pragma unroll
            for (int j = 0; j < 4; ++j) {
                float4 v = p4[j];
                float tmp[4] = { v.x, v.y, v.z, v.w };
                #pragma unroll
                for (int e = 0; e < 4; ++e) {
                    int d = dc * 16 + j * 4 + e;
                    bool msk = (((d < 64) ? (m0 >> d) : (m1 >> (d - 64))) & 1ull) != 0;
                    pm[j * 4 + e] = msk ? 0.0f : tmp[e];
                }
            }
        }
        #pragma unroll
        for (int n = 0; n < ROWS; ++n) {
            const float* __restrict__ r = chunk + n * cD + dc * 16;  // wave-uniform → scalar loads
            #pragma unroll
            for (int i = 0; i < 16; ++i)
                acc[n] = fmaf(r[i], pm[i], acc[n]);
        }
    }

    // --- emit: outlier chains, sign ballots, hash bytes, ip partials ---
    #pragma unroll
    for (int n = 0; n < ROWS; ++n) {
        const int nn = half * ROWS + n;
        const float* __restrict__ r = chunk + n * cD;
        float o = 0.0f;
        #pragma unroll
        for (int k = 0; k < cK; ++k)
            o = fmaf((k < U) ? r[ui[k]] : 0.0f, prO[k], o);

        const bool bitIn = acc[n] > 0.0f;
        unsigned long long mIn  = __ballot(bitIn);
        unsigned long long mOut = __ballot(o > 0.0f);

        float v = bitIn ? qv : -qv;
        #pragma unroll
        for (int off = 32; off > 0; off >>= 1)
            v += __shfl_down(v, off);
        if (lane == 0) ipPart[n * 4 + w] = v;

        if (lane < 8) {
            out[(size_t)b * (cN * 32) + nn * 32 + w * 8 + lane] =
                (float)((mIn >> (8 * lane)) & 0xFFull);
            if (w < 2) {
                out[HASH_OUT_BASE + (size_t)b * (cN * 16) + nn * 16 + w * 8 + lane] =
                    (float)((mOut >> (8 * lane)) & 0xFFull);
            }
        }
    }

    __syncthreads();
    if (t < ROWS) {
        float ip = ipPart[t * 4 + 0] + ipPart[t * 4 + 1]
                 + ipPart[t * 4 + 2] + ipPart[t * 4 + 3];
        const float scl = 0.0048957583f;   // sqrt(pi/2)/256
        out[SCORE_BASE + b * cN + half * ROWS + t] = scl * norm_data[b * cN + half * ROWS + t] * ip;
    }
}

extern "C" void kernel_launch(void* const* d_in, const int* in_sizes, int n_in,
                              void* d_out, int out_size, void* d_ws, size_t ws_size,
                              hipStream_t stream) {
    const float* data      = (const float*)d_in[0];
    const float* query     = (const float*)d_in[1];
    const int*   oidx      = (const int*)d_in[2];
    const float* norm_data = (const float*)d_in[3];
    // d_in[4] = norm_outlier: unused by the reference
    const float* projq     = (const float*)d_in[5];  // proj_dir_quant [S,D]
    const float* projs     = (const float*)d_in[6];  // proj_dir_score [D,S]
    float* out = (float*)d_out;

    float* qv_ws = nullptr;
    if (ws_size >= (size_t)(cH * cS * sizeof(float))) {
        qv_ws = (float*)d_ws;
        qjl_qv<<<cH, cS, 0, stream>>>(query, projs, qv_ws);
    }
    qjl_main<<<cH * cG * 2, 256, 0, stream>>>(data, query, oidx, norm_data,
                                              projq, projs, qv_ws, out);
}

// Round 4
// 350.526 us; speedup vs baseline: 3.1357x; 2.3464x over previous
//
#include <hip/hip_runtime.h>
#include <hip/hip_bf16.h>

// QJLSketch: H=32, G=128, N=64, D=128, S=256, K=8
// d_out (float32, concatenated):
//   [0,        8388608): hash_inlier  [32,128,64,32] byte values as floats
//   [8388608, 12582912): hash_outlier [32,128,64,16] byte values as floats
//   [12582912,12845056): scores       [32, 128*64]
//
// Strategy: bf16 hi/lo split MFMA GEMM (fast approx) + exact f32-chain fixup for
// |value| < EPS. Non-flagged signs provably match the reference's sequential
// f32 FMA chain; flagged ones are recomputed with R3's verified chain semantics.

typedef __attribute__((ext_vector_type(8))) short short8;
typedef __attribute__((ext_vector_type(4))) short short4v;
typedef __attribute__((ext_vector_type(4))) float f32x4;

constexpr int cH = 32, cG = 128, cN = 64, cD = 128, cS = 256, cK = 8;
constexpr int HASH_OUT_BASE = cH * cG * cN * (cS / 8);                  // 8388608
constexpr int SCORE_BASE    = HASH_OUT_BASE + cH * cG * cN * (cS / 16); // 12582912
constexpr float EPS_IN  = 3e-3f;
constexpr float EPS_OUT = 5e-4f;
constexpr size_t WS_BHI = 32768, WS_BLO = 98304, WS_NEED = 163840;

#define MFMA(a, b, c) __builtin_amdgcn_mfma_f32_16x16x32_bf16(a, b, c, 0, 0, 0)

__device__ inline short f2bf(float x) {
    __hip_bfloat16 h = __float2bfloat16(x);            // RNE
    return __builtin_bit_cast(short, h);
}
__device__ inline float bf2f(short s) {
    return __bfloat162float(__builtin_bit_cast(__hip_bfloat16, s));
}
__device__ inline unsigned long long sel4(unsigned long long a0, unsigned long long a1,
                                          unsigned long long a2, unsigned long long a3, int r) {
    unsigned long long x = a0;
    x = (r == 1) ? a1 : x; x = (r == 2) ? a2 : x; x = (r == 3) ? a3 : x;
    return x;
}

// --- precompute: sketched_q[h][s] (sequential chain; scores have 2% tol) ---
__global__ __launch_bounds__(256) void qjl_qv(
    const float* __restrict__ query, const float* __restrict__ projs,
    float* __restrict__ qv_out)
{
    const int h = blockIdx.x, s = threadIdx.x;
    float qa = 0.0f;
    for (int d = 0; d < cD; ++d)
        qa = fmaf(query[h * cD + d], projs[d * cS + s], qa);
    qv_out[h * cS + s] = qa;
}

// --- precompute: B fragments (projq hi/lo bf16) in MFMA lane order ---
// B[k][s] = projq[s][k]; fragment idx = (ksub*16 + nt)*64 + lane;
// lane holds cols s = nt*16 + (lane&15), k = ksub*32 + (lane>>4)*8 + j.
__global__ __launch_bounds__(256) void qjl_bfrag(
    const float* __restrict__ projq, short* __restrict__ bhi, short* __restrict__ blo)
{
    const int idx = blockIdx.x * 256 + threadIdx.x;    // [0, 4096)
    const int l = idx & 63, nt = (idx >> 6) & 15, ksub = idx >> 10;
    const int s = nt * 16 + (l & 15);
    const int k0 = ksub * 32 + (l >> 4) * 8;
    #pragma unroll
    for (int j = 0; j < 8; ++j) {
        float x = projq[s * cD + k0 + j];
        short h = f2bf(x);
        bhi[idx * 8 + j] = h;
        blo[idx * 8 + j] = f2bf(x - bf2f(h));
    }
}

__global__ __launch_bounds__(256) void qjl_mfma(
    const float* __restrict__ data, const int* __restrict__ oidx,
    const float* __restrict__ norm_data, const float* __restrict__ projq,
    const float* __restrict__ qv_ws, const short* __restrict__ bhi_ws,
    const short* __restrict__ blo_ws, float* __restrict__ out)
{
    const int b = blockIdx.x;        // h*G + g
    const int t = threadIdx.x;
    const int lane = t & 63;
    const int w = t >> 6;            // wave owns nt = 4w..4w+3 (s-range 64w..64w+63)
    const int h = b >> 7;

    __shared__ short A_hi[4 * 4 * 64 * 8];   // [ksub][mt][lane][j]  16 KB
    __shared__ short A_lo[4 * 4 * 64 * 8];   // 16 KB
    __shared__ short Ao[4 * 64 * 8];         // [mt][lane][j]  4 KB
    __shared__ short Bo[16 * 64 * 8];        // [nt][lane][j]  16 KB
    __shared__ float ipPart[cN * 4];

    // --- unique outlier indices, sorted (per-thread redundant, as R3) ---
    int u[cK]; int U = 0;
    for (int k = 0; k < cK; ++k) {
        int v = oidx[b * cK + k];
        bool dup = false;
        for (int j = 0; j < U; ++j) dup = dup || (u[j] == v);
        if (!dup) u[U++] = v;
    }
    for (int i = 1; i < U; ++i) {
        int key = u[i], j = i - 1;
        while (j >= 0 && u[j] > key) { u[j + 1] = u[j]; --j; }
        u[j + 1] = key;
    }
    unsigned long long m0 = 0, m1 = 0;
    for (int k = 0; k < U; ++k) {
        int v = u[k];
        if (v < 64) m0 |= 1ull << v; else m1 |= 1ull << (v - 64);
    }

    const float* __restrict__ chunk = data + (size_t)b * (cN * cD);

    // --- A staging: f32 -> bf16 hi/lo in fragment order ---
    #pragma unroll
    for (int i = 0; i < 8; ++i) {
        int f = i * 256 + t;                       // float4 index over 64x128 tile
        float4 v = reinterpret_cast<const float4*>(chunk)[f];
        int row = f >> 5;                          // 32 float4 per row
        int k0  = (f & 31) * 4;
        int mt = row >> 4, il = row & 15;
        int ksub = k0 >> 5, oct = (k0 >> 3) & 3, j = k0 & 7;   // j in {0,4}
        float xs[4] = { v.x, v.y, v.z, v.w };
        short hs[4], ls[4];
        #pragma unroll
        for (int e = 0; e < 4; ++e) {
            hs[e] = f2bf(xs[e]);
            ls[e] = f2bf(xs[e] - bf2f(hs[e]));
        }
        int base = ((ksub * 4 + mt) * 64 + oct * 16 + il) * 8 + j;
        *reinterpret_cast<short4v*>(&A_hi[base]) = short4v{ hs[0], hs[1], hs[2], hs[3] };
        *reinterpret_cast<short4v*>(&A_lo[base]) = short4v{ ls[0], ls[1], ls[2], ls[3] };
    }
    // --- Ao staging (outlier-gathered data, K'=32: [hi|hi|lo|0]) ---
    if (t < cN) {
        int row = t, mt = row >> 4, il = row & 15;
        short ah[8], al[8];
        #pragma unroll
        for (int k = 0; k < cK; ++k) {
            float x = (k < U) ? chunk[row * cD + u[k]] : 0.0f;
            ah[k] = f2bf(x);
            al[k] = f2bf(x - bf2f(ah[k]));
        }
        short8 h8 = { ah[0], ah[1], ah[2], ah[3], ah[4], ah[5], ah[6], ah[7] };
        short8 l8 = { al[0], al[1], al[2], al[3], al[4], al[5], al[6], al[7] };
        short8 z8 = { 0, 0, 0, 0, 0, 0, 0, 0 };
        *reinterpret_cast<short8*>(&Ao[(mt * 64 +  0 + il) * 8]) = h8;
        *reinterpret_cast<short8*>(&Ao[(mt * 64 + 16 + il) * 8]) = h8;
        *reinterpret_cast<short8*>(&Ao[(mt * 64 + 32 + il) * 8]) = l8;
        *reinterpret_cast<short8*>(&Ao[(mt * 64 + 48 + il) * 8]) = z8;
    }
    // --- Bo staging (outlier-gathered projq, K'=32: [hi|lo|hi|0]) ---
    {
        int nt = t >> 4, sc = t & 15, s = nt * 16 + sc;
        short bh[8], bl[8];
        #pragma unroll
        for (int k = 0; k < cK; ++k) {
            float x = (k < U) ? projq[s * cD + u[k]] : 0.0f;
            bh[k] = f2bf(x);
            bl[k] = f2bf(x - bf2f(bh[k]));
        }
        short8 h8 = { bh[0], bh[1], bh[2], bh[3], bh[4], bh[5], bh[6], bh[7] };
        short8 l8 = { bl[0], bl[1], bl[2], bl[3], bl[4], bl[5], bl[6], bl[7] };
        short8 z8 = { 0, 0, 0, 0, 0, 0, 0, 0 };
        *reinterpret_cast<short8*>(&Bo[(nt * 64 +  0 + sc) * 8]) = h8;
        *reinterpret_cast<short8*>(&Bo[(nt * 64 + 16 + sc) * 8]) = l8;
        *reinterpret_cast<short8*>(&Bo[(nt * 64 + 32 + sc) * 8]) = h8;
        *reinterpret_cast<short8*>(&Bo[(nt * 64 + 48 + sc) * 8]) = z8;
    }
    __syncthreads();

    f32x4 acc[16];
    const f32x4 zero4 = { 0.f, 0.f, 0.f, 0.f };

    // --- phase 1: outlier GEMM (sk_out approx) ---
    {
        short8 aO[4], bO[4];
        #pragma unroll
        for (int mt = 0; mt < 4; ++mt)
            aO[mt] = *reinterpret_cast<const short8*>(&Ao[(mt * 64 + lane) * 8]);
        #pragma unroll
        for (int q = 0; q < 4; ++q)
            bO[q] = *reinterpret_cast<const short8*>(&Bo[((w * 4 + q) * 64 + lane) * 8]);
        #pragma unroll
        for (int mt = 0; mt < 4; ++mt)
            #pragma unroll
            for (int q = 0; q < 4; ++q)
                acc[mt * 4 + q] = MFMA(aO[mt], bO[q], zero4);
    }

    // --- phase 2: hash_outlier (s < 128 -> waves 0,1), with exact fixup ---
    if (w < 2) {
        #pragma unroll
        for (int mt = 0; mt < 4; ++mt) {
            #pragma unroll
            for (int q = 0; q < 4; ++q) {
                unsigned long long b0, b1, b2, b3;
                #pragma unroll
                for (int r = 0; r < 4; ++r) {
                    float v = acc[mt * 4 + q][r];
                    if (fabsf(v) < EPS_OUT) {
                        int row = mt * 16 + 4 * (lane >> 4) + r;
                        int s = (w * 4 + q) * 16 + (lane & 15);
                        const float* dr = chunk + row * cD;
                        const float* pr = projq + s * cD;
                        float o = 0.0f;
                        for (int k = 0; k < cK; ++k)
                            if (k < U) o = fmaf(dr[u[k]], pr[u[k]], o);
                        v = o;
                    }
                    unsigned long long bal = __ballot(v > 0.0f);
                    if (r == 0) b0 = bal; else if (r == 1) b1 = bal;
                    else if (r == 2) b2 = bal; else b3 = bal;
                }
                if (lane < 32) {
                    int r = lane & 3, g = (lane >> 2) & 3, hb = lane >> 4;
                    unsigned long long bb = sel4(b0, b1, b2, b3, r);
                    int row = mt * 16 + 4 * g + r;
                    out[HASH_OUT_BASE + (size_t)b * (cN * 16) + row * 16 + (w * 4 + q) * 2 + hb] =
                        (float)((bb >> (16 * g + 8 * hb)) & 0xFFull);
                }
            }
        }
    }

    // --- negate: acc becomes -sk_out, then accumulate full GEMM -> sk_in approx ---
    #pragma unroll
    for (int i = 0; i < 16; ++i)
        #pragma unroll
        for (int r = 0; r < 4; ++r)
            acc[i][r] = -acc[i][r];

    // --- phase 3: main GEMM, K' = 384 = [hi*Bhi | hi*Blo | lo*Bhi] ---
    #pragma unroll
    for (int ksub = 0; ksub < 4; ++ksub) {
        short8 a[4];
        #pragma unroll
        for (int mt = 0; mt < 4; ++mt)
            a[mt] = *reinterpret_cast<const short8*>(&A_hi[((ksub * 4 + mt) * 64 + lane) * 8]);
        #pragma unroll
        for (int q = 0; q < 4; ++q) {
            short8 bh = *reinterpret_cast<const short8*>(
                &bhi_ws[((ksub * 16 + w * 4 + q) * 64 + lane) * 8]);
            #pragma unroll
            for (int mt = 0; mt < 4; ++mt)
                acc[mt * 4 + q] = MFMA(a[mt], bh, acc[mt * 4 + q]);
        }
        #pragma unroll
        for (int q = 0; q < 4; ++q) {
            short8 bl = *reinterpret_cast<const short8*>(
                &blo_ws[((ksub * 16 + w * 4 + q) * 64 + lane) * 8]);
            #pragma unroll
            for (int mt = 0; mt < 4; ++mt)
                acc[mt * 4 + q] = MFMA(a[mt], bl, acc[mt * 4 + q]);
        }
    }
    #pragma unroll
    for (int ksub = 0; ksub < 4; ++ksub) {
        short8 a[4];
        #pragma unroll
        for (int mt = 0; mt < 4; ++mt)
            a[mt] = *reinterpret_cast<const short8*>(&A_lo[((ksub * 4 + mt) * 64 + lane) * 8]);
        #pragma unroll
        for (int q = 0; q < 4; ++q) {
            short8 bh = *reinterpret_cast<const short8*>(
                &bhi_ws[((ksub * 16 + w * 4 + q) * 64 + lane) * 8]);
            #pragma unroll
            for (int mt = 0; mt < 4; ++mt)
                acc[mt * 4 + q] = MFMA(a[mt], bh, acc[mt * 4 + q]);
        }
    }

    // --- phase 4: hash_inlier + ip partials, with exact-chain fixup ---
    float qvv[4];
    #pragma unroll
    for (int q = 0; q < 4; ++q)
        qvv[q] = qv_ws[h * cS + (w * 4 + q) * 16 + (lane & 15)];
    float part[4][4];
    #pragma unroll
    for (int mt = 0; mt < 4; ++mt)
        #pragma unroll
        for (int r = 0; r < 4; ++r) part[mt][r] = 0.0f;

    #pragma unroll
    for (int mt = 0; mt < 4; ++mt) {
        #pragma unroll
        for (int q = 0; q < 4; ++q) {
            unsigned long long b0, b1, b2, b3;
            #pragma unroll
            for (int r = 0; r < 4; ++r) {
                float v = acc[mt * 4 + q][r];
                if (fabsf(v) < EPS_IN) {
                    int row = mt * 16 + 4 * (lane >> 4) + r;
                    int s = (w * 4 + q) * 16 + (lane & 15);
                    const float* dr = chunk + row * cD;
                    const float* pr = projq + s * cD;
                    float ex = 0.0f;
                    for (int d = 0; d < cD; ++d) {
                        bool msk = ((((d < 64) ? (m0 >> d) : (m1 >> (d - 64))) & 1ull) != 0);
                        float pv = msk ? 0.0f : pr[d];
                        ex = fmaf(dr[d], pv, ex);
                    }
                    v = ex;
                }
                bool bit = v > 0.0f;
                unsigned long long bal = __ballot(bit);
                part[mt][r] += bit ? qvv[q] : -qvv[q];
                if (r == 0) b0 = bal; else if (r == 1) b1 = bal;
                else if (r == 2) b2 = bal; else b3 = bal;
            }
            if (lane < 32) {
                int r = lane & 3, g = (lane >> 2) & 3, hb = lane >> 4;
                unsigned long long bb = sel4(b0, b1, b2, b3, r);
                int row = mt * 16 + 4 * g + r;
                out[(size_t)b * (cN * 32) + row * 32 + (w * 4 + q) * 2 + hb] =
                    (float)((bb >> (16 * g + 8 * hb)) & 0xFFull);
            }
        }
    }

    // --- ip reduction: xor-tree over the 16 lanes sharing a row ---
    #pragma unroll
    for (int mt = 0; mt < 4; ++mt) {
        #pragma unroll
        for (int r = 0; r < 4; ++r) {
            float x = part[mt][r];
            x += __shfl_xor(x, 1); x += __shfl_xor(x, 2);
            x += __shfl_xor(x, 4); x += __shfl_xor(x, 8);
            if ((lane & 15) == 0)
                ipPart[(mt * 16 + 4 * (lane >> 4) + r) * 4 + w] = x;
        }
    }
    __syncthreads();
    if (t < cN) {
        float ip = ipPart[t * 4 + 0] + ipPart[t * 4 + 1]
                 + ipPart[t * 4 + 2] + ipPart[t * 4 + 3];
        const float scl = 0.0048957583f;   // sqrt(pi/2)/256
        out[SCORE_BASE + b * cN + t] = scl * norm_data[b * cN + t] * ip;
    }
}

// ---------------- fallback (R3 kernel, passed): used if ws too small ----------------
__global__ __launch_bounds__(256) void qjl_valu(
    const float* __restrict__ data, const float* __restrict__ query,
    const int* __restrict__ oidx, const float* __restrict__ norm_data,
    const float* __restrict__ projq, const float* __restrict__ projs,
    float* __restrict__ out)
{
    const int b2 = blockIdx.x, b = b2 >> 1, half = b2 & 1;
    const int t = threadIdx.x, lane = t & 63, w = t >> 6, h = b >> 7;
    __shared__ float ipPart[32 * 4];
    int u[cK]; int U = 0;
    for (int k = 0; k < cK; ++k) {
        int v = oidx[b * cK + k];
        bool dup = false;
        for (int j = 0; j < U; ++j) dup = dup || (u[j] == v);
        if (!dup) u[U++] = v;
    }
    for (int i = 1; i < U; ++i) {
        int key = u[i], j = i - 1;
        while (j >= 0 && u[j] > key) { u[j + 1] = u[j]; --j; }
        u[j + 1] = key;
    }
    unsigned long long m0 = 0, m1 = 0;
    for (int k = 0; k < U; ++k) {
        int v = u[k];
        if (v < 64) m0 |= 1ull << v; else m1 |= 1ull << (v - 64);
    }
    int ui[cK]; float prO[cK];
    #pragma unroll
    for (int k = 0; k < cK; ++k) ui[k] = (k < U) ? u[k] : 0;
    #pragma unroll
    for (int k = 0; k < cK; ++k) prO[k] = (k < U) ? projq[t * cD + ui[k]] : 0.0f;
    float qv = 0.0f;
    for (int d = 0; d < cD; ++d)
        qv = fmaf(query[h * cD + d], projs[d * cS + t], qv);
    const float* __restrict__ chunk = data + (size_t)b * (cN * cD) + half * (32 * cD);
    float acc[32];
    #pragma unroll
    for (int n = 0; n < 32; ++n) acc[n] = 0.0f;
    for (int dc = 0; dc < cD / 16; ++dc) {
        float pm[16];
        const float4* p4 = reinterpret_cast<const float4*>(projq + t * cD + dc * 16);
        #pragma unroll
        for (int j = 0; j < 4; ++j) {
            float4 v = p4[j];
            float tmp[4] = { v.x, v.y, v.z, v.w };
            #pragma unroll
            for (int e = 0; e < 4; ++e) {
                int d = dc * 16 + j * 4 + e;
                bool msk = (((d < 64) ? (m0 >> d) : (m1 >> (d - 64))) & 1ull) != 0;
                pm[j * 4 + e] = msk ? 0.0f : tmp[e];
            }
        }
        #pragma unroll
        for (int n = 0; n < 32; ++n) {
            const float* __restrict__ r = chunk + n * cD + dc * 16;
            #pragma unroll
            for (int i = 0; i < 16; ++i)
                acc[n] = fmaf(r[i], pm[i], acc[n]);
        }
    }
    #pragma unroll
    for (int n = 0; n < 32; ++n) {
        const int nn = half * 32 + n;
        const float* __restrict__ r = chunk + n * cD;
        float o = 0.0f;
        #pragma unroll
        for (int k = 0; k < cK; ++k)
            o = fmaf((k < U) ? r[ui[k]] : 0.0f, prO[k], o);
        const bool bitIn = acc[n] > 0.0f;
        unsigned long long mIn = __ballot(bitIn);
        unsigned long long mOut = __ballot(o > 0.0f);
        float v = bitIn ? qv : -qv;
        #pragma unroll
        for (int off = 32; off > 0; off >>= 1) v += __shfl_down(v, off);
        if (lane == 0) ipPart[n * 4 + w] = v;
        if (lane < 8) {
            out[(size_t)b * (cN * 32) + nn * 32 + w * 8 + lane] =
                (float)((mIn >> (8 * lane)) & 0xFFull);
            if (w < 2)
                out[HASH_OUT_BASE + (size_t)b * (cN * 16) + nn * 16 + w * 8 + lane] =
                    (float)((mOut >> (8 * lane)) & 0xFFull);
        }
    }
    __syncthreads();
    if (t < 32) {
        float ip = ipPart[t * 4 + 0] + ipPart[t * 4 + 1] + ipPart[t * 4 + 2] + ipPart[t * 4 + 3];
        out[SCORE_BASE + b * cN + half * 32 + t] = 0.0048957583f * norm_data[b * cN + half * 32 + t] * ip;
    }
}

extern "C" void kernel_launch(void* const* d_in, const int* in_sizes, int n_in,
                              void* d_out, int out_size, void* d_ws, size_t ws_size,
                              hipStream_t stream) {
    const float* data      = (const float*)d_in[0];
    const float* query     = (const float*)d_in[1];
    const int*   oidx      = (const int*)d_in[2];
    const float* norm_data = (const float*)d_in[3];
    // d_in[4] = norm_outlier: unused by the reference
    const float* projq     = (const float*)d_in[5];  // proj_dir_quant [S,D]
    const float* projs     = (const float*)d_in[6];  // proj_dir_score [D,S]
    float* out = (float*)d_out;

    if (ws_size >= WS_NEED) {
        float* qv  = (float*)d_ws;
        short* bhi = (short*)((char*)d_ws + WS_BHI);
        short* blo = (short*)((char*)d_ws + WS_BLO);
        qjl_qv<<<cH, cS, 0, stream>>>(query, projs, qv);
        qjl_bfrag<<<16, 256, 0, stream>>>(projq, bhi, blo);
        qjl_mfma<<<cH * cG, 256, 0, stream>>>(data, oidx, norm_data, projq,
                                              qv, bhi, blo, out);
    } else {
        qjl_valu<<<cH * cG * 2, 256, 0, stream>>>(data, query, oidx, norm_data,
                                                  projq, projs, out);
    }
}